// Round 3
// baseline (5952.832 us; speedup 1.0000x reference)
//
#include <hip/hip_runtime.h>
#include <hip/hip_bf16.h>

#define NM 4096
#define DD 256
constexpr float PCONST = 1.0f / 4096.0f;   // p = q = 1/n
#define NPAIR 6                            // sinkhorn pairs (converged ≡ 50 by contraction)

typedef __attribute__((ext_vector_type(8))) _Float16 f16x8;
typedef __attribute__((ext_vector_type(4))) float f32x4;

// ---------------- prep: z = (x - mean) / ||x - mean||, fp16 ----------------
__global__ void prep_z(const float* __restrict__ ft, const float* __restrict__ fs,
                       _Float16* __restrict__ zt, _Float16* __restrict__ zs) {
    int row = blockIdx.x;                 // 0..8191
    int tid = threadIdx.x;                // 256 == DD
    const float* src = (row < NM) ? (ft + (size_t)row * DD) : (fs + (size_t)(row - NM) * DD);
    _Float16* dst = (row < NM) ? (zt + (size_t)row * DD) : (zs + (size_t)(row - NM) * DD);
    float x = src[tid];
    __shared__ float red[4];
    float s = x;
    for (int o = 32; o > 0; o >>= 1) s += __shfl_xor(s, o);
    if ((tid & 63) == 0) red[tid >> 6] = s;
    __syncthreads();
    float mean = (red[0] + red[1] + red[2] + red[3]) * (1.0f / DD);
    float mc = x - mean;
    __syncthreads();
    float q = mc * mc;
    for (int o = 32; o > 0; o >>= 1) q += __shfl_xor(q, o);
    if ((tid & 63) == 0) red[tid >> 6] = q;
    __syncthreads();
    float ss = red[0] + red[1] + red[2] + red[3];
    float scale = 1.0f / sqrtf(ss);
    dst[tid] = (_Float16)(mc * scale);
}

// ---------------- init kernels ----------------
__global__ void init_misc(float* ra, float* rb, float* u, float* v, float* gmout) {
    int i = blockIdx.x * 256 + threadIdx.x;     // grid 16 -> 4096
    ra[i] = 0.f; rb[i] = 0.f; u[i] = PCONST; v[i] = PCONST;
    if (i == 0) gmout[0] = 0.f;
}
__global__ void init_S(_Float16* __restrict__ S) {
    size_t idx = ((size_t)blockIdx.x * 256 + threadIdx.x) * 8;  // grid 8192 -> exactly 16.8M
    f16x8 one;
    #pragma unroll
    for (int e = 0; e < 8; ++e) one[e] = (_Float16)1.0f;
    *(f16x8*)(S + idx) = one;
}

// ---------------- A' = Ca (.) u (column scale), fp16 ----------------
__global__ void scale_A(const _Float16* __restrict__ Ca, const float* __restrict__ u,
                        _Float16* __restrict__ Ap) {
    size_t base = ((size_t)blockIdx.x * 256 + threadIdx.x) * 8;
    size_t stride = (size_t)gridDim.x * 256 * 8;
    size_t total = (size_t)NM * NM;
    for (size_t idx = base; idx < total; idx += stride) {
        f16x8 c8 = *(const f16x8*)(Ca + idx);
        int k = (int)(idx & (NM - 1));
        f16x8 o8;
        #pragma unroll
        for (int e = 0; e < 8; ++e) o8[e] = (_Float16)((float)c8[e] * u[k + e]);
        *(f16x8*)(Ap + idx) = o8;
    }
}

// ---------------- BT-GEMM, 128x128 tile, BK=32, m97 structure ----------------
// out[row][col] = sum_k A[row][k] * B[col][k]      (A,B fp16 row-major, stride K)
// MODE 0: Cout = f16(1 - acc) (=Ca/Cb), atomic row-mean-of-squares into rsum_out
// MODE 1: Cout = f16(acc * sv[col])                (P' with v column scale)
// MODE 2: tens = ra[col]+rb[row]-2*acc; Cout = f16(exp(-2*tens))   (S_new = K_new^T)
// MODE 3: tens as MODE2; T = su[col]*S[row][col]*sv[row]; atomicAdd(gm, sum tens*T)
template<int MODE>
__global__ void __launch_bounds__(256)
gemm_bt(const _Float16* __restrict__ A, const _Float16* __restrict__ B,
        int K, _Float16* __restrict__ Cout,
        const float* __restrict__ ra, const float* __restrict__ rb,
        float* __restrict__ rsum_out,
        const float* __restrict__ su, const float* __restrict__ sv,
        const _Float16* __restrict__ Smat, float* __restrict__ gm)
{
    __shared__ _Float16 As[128 * 32];
    __shared__ _Float16 Bs[128 * 32];
    int tid = threadIdx.x;
    int bi = blockIdx.x & 31, bj = blockIdx.x >> 5;
    int row0 = bi * 128, col0 = bj * 128;
    int lane = tid & 63;
    int w = tid >> 6, wr = w >> 1, wc = w & 1;

    f32x4 acc[4][4] = {};

    int e0 = tid * 8, e1 = e0 + 2048;
    const _Float16* Ap0 = A + (size_t)(row0 + (e0 >> 5)) * K + (e0 & 31);
    const _Float16* Ap1 = A + (size_t)(row0 + (e1 >> 5)) * K + (e1 & 31);
    const _Float16* Bp0 = B + (size_t)(col0 + (e0 >> 5)) * K + (e0 & 31);
    const _Float16* Bp1 = B + (size_t)(col0 + (e1 >> 5)) * K + (e1 & 31);

    int ar = lane & 15, ko = (lane >> 4) * 8;

    for (int k0 = 0; k0 < K; k0 += 32) {
        __builtin_amdgcn_global_load_lds(
            (const __attribute__((address_space(1))) unsigned int*)(Ap0 + k0),
            (__attribute__((address_space(3))) unsigned int*)(As + e0), 16, 0, 0);
        __builtin_amdgcn_global_load_lds(
            (const __attribute__((address_space(1))) unsigned int*)(Ap1 + k0),
            (__attribute__((address_space(3))) unsigned int*)(As + e1), 16, 0, 0);
        __builtin_amdgcn_global_load_lds(
            (const __attribute__((address_space(1))) unsigned int*)(Bp0 + k0),
            (__attribute__((address_space(3))) unsigned int*)(Bs + e0), 16, 0, 0);
        __builtin_amdgcn_global_load_lds(
            (const __attribute__((address_space(1))) unsigned int*)(Bp1 + k0),
            (__attribute__((address_space(3))) unsigned int*)(Bs + e1), 16, 0, 0);
        __syncthreads();

        f16x8 av[4], bv[4];
        #pragma unroll
        for (int m = 0; m < 4; ++m) av[m] = *(const f16x8*)&As[(wr * 64 + m * 16 + ar) * 32 + ko];
        #pragma unroll
        for (int n = 0; n < 4; ++n) bv[n] = *(const f16x8*)&Bs[(wc * 64 + n * 16 + ar) * 32 + ko];
        #pragma unroll
        for (int m = 0; m < 4; ++m)
            #pragma unroll
            for (int n = 0; n < 4; ++n)
                acc[m][n] = __builtin_amdgcn_mfma_f32_16x16x32_f16(av[m], bv[n], acc[m][n], 0, 0, 0);
        __syncthreads();
    }

    // epilogue: C/D layout (m89-verified): col = lane&15, row = (lane>>4)*4 + r
    int rbase = row0 + wr * 64, cbase = col0 + wc * 64;
    int lrow4 = (lane >> 4) * 4, lcol = lane & 15;
    float lsum = 0.f;
    #pragma unroll
    for (int m = 0; m < 4; ++m) {
        #pragma unroll
        for (int r = 0; r < 4; ++r) {
            int orow = rbase + m * 16 + lrow4 + r;
            float rowacc = 0.f;
            #pragma unroll
            for (int n = 0; n < 4; ++n) {
                int ocol = cbase + n * 16 + lcol;
                float val = acc[m][n][r];
                if constexpr (MODE == 0) {
                    _Float16 hb = (_Float16)(1.0f - val);
                    Cout[(size_t)orow * NM + ocol] = hb;
                    float fb = (float)hb;
                    rowacc += fb * fb;
                } else if constexpr (MODE == 1) {
                    Cout[(size_t)orow * NM + ocol] = (_Float16)(val * sv[ocol]);
                } else if constexpr (MODE == 2) {
                    float tens = ra[ocol] + rb[orow] - 2.0f * val;
                    Cout[(size_t)orow * NM + ocol] = (_Float16)expf(-2.0f * tens);
                } else {
                    float tens = ra[ocol] + rb[orow] - 2.0f * val;
                    float tv = su[ocol] * (float)Smat[(size_t)orow * NM + ocol] * sv[orow];
                    lsum += tens * tv;
                }
            }
            if constexpr (MODE == 0) {
                rowacc += __shfl_xor(rowacc, 1);
                rowacc += __shfl_xor(rowacc, 2);
                rowacc += __shfl_xor(rowacc, 4);
                rowacc += __shfl_xor(rowacc, 8);
                if (lcol == 0) atomicAdd(&rsum_out[orow], rowacc * PCONST);
            }
        }
    }
    if constexpr (MODE == 3) {
        for (int o = 32; o > 0; o >>= 1) lsum += __shfl_xor(lsum, o);
        __shared__ float redm[4];
        if (lane == 0) redm[w] = lsum;
        __syncthreads();
        if (tid == 0) atomicAdd(gm, redm[0] + redm[1] + redm[2] + redm[3]);
    }
}

// ---------------- transpose: STr[i][j] = S[j][i] (fp16, 64x64 tiles) ----------------
__global__ void __launch_bounds__(256)
transpose16(const _Float16* __restrict__ S, _Float16* __restrict__ STr) {
    __shared__ _Float16 tile[64][65];
    int b = blockIdx.x;                  // 4096 = 64 x 64 tiles
    int jb = b >> 6, ib = b & 63;
    int j0 = jb * 64, i0 = ib * 64;
    int tid = threadIdx.x;
    int r = tid >> 2, c0 = (tid & 3) * 16;
    // load S[(j0+r)][i0+c0 .. +15]
    f16x8 v0 = *(const f16x8*)(S + (size_t)(j0 + r) * NM + i0 + c0);
    f16x8 v1 = *(const f16x8*)(S + (size_t)(j0 + r) * NM + i0 + c0 + 8);
    #pragma unroll
    for (int e = 0; e < 8; ++e) { tile[r][c0 + e] = v0[e]; tile[r][c0 + 8 + e] = v1[e]; }
    __syncthreads();
    // write STr[(i0+r)][j0+c0 .. +15] = tile[c0+e][r]
    f16x8 o0, o1;
    #pragma unroll
    for (int e = 0; e < 8; ++e) { o0[e] = tile[c0 + e][r]; o1[e] = tile[c0 + 8 + e][r]; }
    *(f16x8*)(STr + (size_t)(i0 + r) * NM + j0 + c0) = o0;
    *(f16x8*)(STr + (size_t)(i0 + r) * NM + j0 + c0 + 8) = o1;
}

// ---------------- sinkhorn matvec: rout[j] = PCONST / dot(M[j,:], rin) ----------------
// FIRST=1: rin treated as all-ones (u0 = ones)
template<int FIRST>
__global__ void __launch_bounds__(256)
matvec_row(const _Float16* __restrict__ M, const float* __restrict__ rin,
           float* __restrict__ rout) {
    int j = blockIdx.x;                  // 4096 rows
    int tid = threadIdx.x;
    const _Float16* row = M + (size_t)j * NM + tid * 16;
    float s = 0.f;
    f16x8 a0 = *(const f16x8*)(row);
    f16x8 a1 = *(const f16x8*)(row + 8);
    if constexpr (FIRST) {
        #pragma unroll
        for (int e = 0; e < 8; ++e) s += (float)a0[e] + (float)a1[e];
    } else {
        const float* rp = rin + tid * 16;
        f32x4 r0 = *(const f32x4*)(rp);
        f32x4 r1 = *(const f32x4*)(rp + 4);
        f32x4 r2 = *(const f32x4*)(rp + 8);
        f32x4 r3 = *(const f32x4*)(rp + 12);
        #pragma unroll
        for (int e = 0; e < 4; ++e) {
            s += (float)a0[e] * r0[e];
            s += (float)a0[e + 4] * r1[e];
            s += (float)a1[e] * r2[e];
            s += (float)a1[e + 4] * r3[e];
        }
    }
    for (int o = 32; o > 0; o >>= 1) s += __shfl_xor(s, o);
    __shared__ float red[4];
    if ((tid & 63) == 0) red[tid >> 6] = s;
    __syncthreads();
    if (tid == 0) rout[j] = PCONST / (red[0] + red[1] + red[2] + red[3]);
}

// ---------------- write T = u (.) K (.) v, row-major via LDS transpose ----------------
__global__ void write_T(const _Float16* __restrict__ S, const float* __restrict__ u,
                        const float* __restrict__ v, float* __restrict__ T) {
    __shared__ float tile[64][65];
    int b = blockIdx.x;                  // 4096 = 64 x 64 tiles
    int jb = b >> 6, ibk = b & 63;
    int j0 = jb * 64, i0 = ibk * 64;
    int tid = threadIdx.x;
    #pragma unroll
    for (int it = 0; it < 16; ++it) {
        int lin = it * 256 + tid;
        int jr = lin >> 6, ic = lin & 63;
        tile[jr][ic] = u[i0 + ic] * (float)S[(size_t)(j0 + jr) * NM + i0 + ic] * v[j0 + jr];
    }
    __syncthreads();
    #pragma unroll
    for (int it = 0; it < 16; ++it) {
        int lin = it * 256 + tid;
        int ir = lin >> 6, jc = lin & 63;
        T[(size_t)(i0 + ir) * NM + j0 + jc] = tile[jc][ir];
    }
}

// ---------------- host launcher ----------------
extern "C" void kernel_launch(void* const* d_in, const int* in_sizes, int n_in,
                              void* d_out, int out_size, void* d_ws, size_t ws_size,
                              hipStream_t stream) {
    const float* ft = (const float*)d_in[0];
    const float* fs = (const float*)d_in[1];
    float* out = (float*)d_out;
    char* ws = (char*)d_ws;

    _Float16* Ca = (_Float16*)(ws);                  // 32MB
    _Float16* Cb = (_Float16*)(ws + 33554432);       // 32MB
    _Float16* S  = (_Float16*)(ws + 67108864);       // 32MB (= K^T)
    _Float16* Pp = (_Float16*)(ws + 100663296);      // 32MB
    _Float16* zt = (_Float16*)(ws + 134217728);      // 2MB
    _Float16* zs = (_Float16*)(ws + 136314880);      // 2MB
    float* ra = (float*)(ws + 138412032);
    float* rb = ra + 4096;
    float* u  = ra + 8192;                           // == r_u (sinkhorn u)
    float* v  = ra + 12288;                          // == r_v (sinkhorn v)
    // Ap (iter-local GEMM A-operand) and STr (K row-major, sinkhorn-local) share
    // the regenerated-every-iter scratch inside d_out's T region; lifetimes disjoint.
    _Float16* Ap  = (_Float16*)(out + 4);            // 32MB, 16B aligned
    _Float16* STr = Ap;                              // same region

    init_misc<<<16, 256, 0, stream>>>(ra, rb, u, v, out);
    prep_z<<<8192, 256, 0, stream>>>(ft, fs, zt, zs);
    gemm_bt<0><<<1024, 256, 0, stream>>>(zt, zt, DD, Ca, nullptr, nullptr, ra,
                                         nullptr, nullptr, nullptr, nullptr);
    gemm_bt<0><<<1024, 256, 0, stream>>>(zs, zs, DD, Cb, nullptr, nullptr, rb,
                                         nullptr, nullptr, nullptr, nullptr);
    init_S<<<8192, 256, 0, stream>>>(S);

    for (int t = 0; t < 10; ++t) {
        // GEMM chain for tens_t, using T_t = u (.) S (.) v
        scale_A<<<2048, 256, 0, stream>>>(Ca, u, Ap);
        gemm_bt<1><<<1024, 256, 0, stream>>>(Ap, S, NM, Pp, nullptr, nullptr, nullptr,
                                             nullptr, v, nullptr, nullptr);
        gemm_bt<2><<<1024, 256, 0, stream>>>(Cb, Pp, NM, S, ra, rb, nullptr,
                                             nullptr, nullptr, nullptr, nullptr);
        // Sinkhorn on K_{t+1}: sequential matvec launches, ping-pong u/v
        transpose16<<<4096, 256, 0, stream>>>(S, STr);
        matvec_row<1><<<4096, 256, 0, stream>>>(S, nullptr, v);     // v1 = q/(K^T 1)
        for (int p = 0; p < NPAIR; ++p) {
            matvec_row<0><<<4096, 256, 0, stream>>>(STr, v, u);     // u = p/(K v)
            matvec_row<0><<<4096, 256, 0, stream>>>(S, u, v);       // v = q/(K^T u)
        }
    }

    // final tens evaluation with T_10, fused gm_loss, then materialize T
    scale_A<<<2048, 256, 0, stream>>>(Ca, u, Ap);
    gemm_bt<1><<<1024, 256, 0, stream>>>(Ap, S, NM, Pp, nullptr, nullptr, nullptr,
                                         nullptr, v, nullptr, nullptr);
    gemm_bt<3><<<1024, 256, 0, stream>>>(Cb, Pp, NM, nullptr, ra, rb, nullptr,
                                         u, v, S, out);
    write_T<<<4096, 256, 0, stream>>>(S, u, v, out + 1);
}

// Round 7
// 3435.067 us; speedup vs baseline: 1.7330x; 1.7330x over previous
//
#include <hip/hip_runtime.h>
#include <hip/hip_bf16.h>

#define NM 4096
#define DD 256
constexpr float PCONST = 1.0f / 4096.0f;   // p = q = 1/n
#define NPAIR 3                            // sinkhorn pairs (converged; contraction ~1.6e-3/pair)
#define GLDS 131072                        // 64KB A + 64KB B (double-buffered)

typedef __attribute__((ext_vector_type(8))) _Float16 f16x8;
typedef __attribute__((ext_vector_type(4))) float f32x4;

// ---------------- prep: z = (x - mean) / ||x - mean||, fp16 ----------------
__global__ void prep_z(const float* __restrict__ ft, const float* __restrict__ fs,
                       _Float16* __restrict__ zt, _Float16* __restrict__ zs) {
    int row = blockIdx.x;                 // 0..8191
    int tid = threadIdx.x;                // 256 == DD
    const float* src = (row < NM) ? (ft + (size_t)row * DD) : (fs + (size_t)(row - NM) * DD);
    _Float16* dst = (row < NM) ? (zt + (size_t)row * DD) : (zs + (size_t)(row - NM) * DD);
    float x = src[tid];
    __shared__ float red[4];
    float s = x;
    for (int o = 32; o > 0; o >>= 1) s += __shfl_xor(s, o);
    if ((tid & 63) == 0) red[tid >> 6] = s;
    __syncthreads();
    float mean = (red[0] + red[1] + red[2] + red[3]) * (1.0f / DD);
    float mc = x - mean;
    __syncthreads();
    float q = mc * mc;
    for (int o = 32; o > 0; o >>= 1) q += __shfl_xor(q, o);
    if ((tid & 63) == 0) red[tid >> 6] = q;
    __syncthreads();
    float ss = red[0] + red[1] + red[2] + red[3];
    float scale = 1.0f / sqrtf(ss);
    dst[tid] = (_Float16)(mc * scale);
}

// ---------------- init kernels ----------------
__global__ void init_misc(float* ra, float* rb, float* u, float* v, float* gmout) {
    int i = blockIdx.x * 256 + threadIdx.x;     // grid 16 -> 4096
    ra[i] = 0.f; rb[i] = 0.f; u[i] = PCONST; v[i] = PCONST;
    if (i == 0) gmout[0] = 0.f;
}
__global__ void init_S(_Float16* __restrict__ S) {
    size_t idx = ((size_t)blockIdx.x * 256 + threadIdx.x) * 8;  // grid 8192
    f16x8 one;
    #pragma unroll
    for (int e = 0; e < 8; ++e) one[e] = (_Float16)1.0f;
    *(f16x8*)(S + idx) = one;
}

// ---------------- A' = Ca (.) u (column scale), fp32 u (decorrelated rounding) ----------------
__global__ void scale_A(const _Float16* __restrict__ Ca, const float* __restrict__ u,
                        _Float16* __restrict__ Ap) {
    size_t base = ((size_t)blockIdx.x * 256 + threadIdx.x) * 8;
    size_t stride = (size_t)gridDim.x * 256 * 8;
    size_t total = (size_t)NM * NM;
    for (size_t idx = base; idx < total; idx += stride) {
        f16x8 c8 = *(const f16x8*)(Ca + idx);
        int k = (int)(idx & (NM - 1));
        f16x8 o8;
        #pragma unroll
        for (int e = 0; e < 8; ++e) o8[e] = (_Float16)((float)c8[e] * u[k + e]);
        *(f16x8*)(Ap + idx) = o8;
    }
}

// =====================================================================
// 8-phase 256x256 BT-GEMM (m201-style), BK=64, 8 waves, 128KB dbuf LDS,
// st_16x32 swizzle (linear dest + inverse-swizzled global src), counted
// vmcnt(4) at phases 4/8, setprio around MFMA clusters.
// out[row][col] = sum_k A[row][k]*B[col][k]  (A,B f16 row-major stride K)
// MODE 0: Cout=f16(1-acc), atomic row-mean-of-squares into rsum_out
// MODE 1: Cout=f16(acc*sv[col])
// MODE 2: tens=ra[col]+rb[row]-2*acc; Cout=f16(exp(-2*tens))
// MODE 3: tens as 2; T=su[col]*Smat[row][col]*sv[row]; atomicAdd(gm,sum)
// =====================================================================
#define BARX do { __builtin_amdgcn_s_barrier(); __builtin_amdgcn_sched_barrier(0); } while(0)
#define VMC4 asm volatile("s_waitcnt vmcnt(4)" ::: "memory")
#define VMC0 asm volatile("s_waitcnt vmcnt(0)" ::: "memory")

#define STAGE(matb, d, h, kt) do { \
    const char* _s = ((matb) ? Bb : Ab) + (size_t)((h) * 128) * lda + (size_t)(kt) * 128; \
    char* _dst = lds + ((matb) ? 65536 : 0) + (d) * 32768 + (h) * 16384; \
    __builtin_amdgcn_global_load_lds((const __attribute__((address_space(1))) unsigned int*)(_s + (size_t)sr0 * lda + sc0), \
        (__attribute__((address_space(3))) unsigned int*)(_dst + P0), 16, 0, 0); \
    __builtin_amdgcn_global_load_lds((const __attribute__((address_space(1))) unsigned int*)(_s + (size_t)sr1 * lda + sc1), \
        (__attribute__((address_space(3))) unsigned int*)(_dst + P1b), 16, 0, 0); \
  } while(0)

#define MFMAQ(MH, NH) do { \
    __builtin_amdgcn_s_setprio(1); \
    _Pragma("unroll") for (int mm = 0; mm < 4; ++mm) \
    _Pragma("unroll") for (int nn = 0; nn < 2; ++nn) \
    _Pragma("unroll") for (int ks = 0; ks < 2; ++ks) \
        acc[(MH)*4+mm][(NH)*2+nn] = __builtin_amdgcn_mfma_f32_16x16x32_f16( \
            av[(MH)*4+mm][ks], bv[(NH)*2+nn][ks], acc[(MH)*4+mm][(NH)*2+nn], 0, 0, 0); \
    __builtin_amdgcn_s_setprio(0); \
  } while(0)

template<int MODE>
__global__ void __launch_bounds__(512, 2)
gemm8p(const _Float16* __restrict__ A, const _Float16* __restrict__ B, const int K,
       _Float16* __restrict__ Cout,
       const float* __restrict__ ra, const float* __restrict__ rb,
       float* __restrict__ rsum_out,
       const float* __restrict__ su, const float* __restrict__ sv,
       const _Float16* __restrict__ Smat, float* __restrict__ gm)
{
    extern __shared__ __align__(16) char lds[];
    const int tid = threadIdx.x;
    const int lane = tid & 63, w = tid >> 6;
    const int wr = w >> 2, wc = w & 3;
    const int bi = blockIdx.x & 15, bj = blockIdx.x >> 4;
    const int row0 = bi * 256, col0 = bj * 256;
    const int l15 = lane & 15, l4 = lane >> 4;
    const int xorm = (lane & 4) << 3;          // swizzle bit5 = row bit2 = lane bit2

    // staging constants: physical chunk P -> logical L (involution st_16x32)
    const int P0 = tid * 16, P1b = P0 + 8192;
    const int Ls0 = P0 ^ (((P0 >> 9) & 1) << 5);
    const int Ls1 = P1b ^ (((P1b >> 9) & 1) << 5);
    const int sr0 = Ls0 >> 7, sc0 = Ls0 & 127;
    const int sr1 = Ls1 >> 7, sc1 = Ls1 & 127;

    const size_t lda = (size_t)K * 2;
    const char* Ab = (const char*)A + (size_t)row0 * lda;
    const char* Bb = (const char*)B + (size_t)col0 * lda;

    // ds_read bases (+ d*32768 + frag*2048 + ks*64)
    const int aB = wr * 16384 + ((l15 * 128 + l4 * 16) ^ xorm);
    const int bB = 65536 + (wc >> 1) * 16384 + ((((wc & 1) * 64 + l15) * 128 + l4 * 16) ^ xorm);

    f32x4 acc[8][4] = {};
    f16x8 av[8][2], bv[4][2];

    // ---- prologue: B(0),A(0),B(1) halves ----
    STAGE(1, 0, 0, 0); STAGE(1, 0, 1, 0);
    STAGE(0, 0, 0, 0); STAGE(0, 0, 1, 0);
    STAGE(1, 1, 0, 1); STAGE(1, 1, 1, 1);
    VMC4;                       // tile0 A+B landed; B(1) in flight
    BARX;

    const int niter = K >> 7;   // K / 128, two K-tiles per iteration
    for (int i = 0; i < niter; ++i) {
        const int kx = 2 * i, ky = kx + 1;
        const bool last = (i == niter - 1);

        // ======== tile kx from buf0 ========
        // P1: read av0-3 + bv0-1; stage A0(ky)->buf1
        #pragma unroll
        for (int mm = 0; mm < 4; ++mm) {
            av[mm][0] = *(const f16x8*)(lds + aB + mm * 2048);
            av[mm][1] = *(const f16x8*)(lds + aB + mm * 2048 + 64);
        }
        #pragma unroll
        for (int nn = 0; nn < 2; ++nn) {
            bv[nn][0] = *(const f16x8*)(lds + bB + nn * 2048);
            bv[nn][1] = *(const f16x8*)(lds + bB + nn * 2048 + 64);
        }
        STAGE(0, 1, 0, ky);
        BARX; MFMAQ(0, 0); BARX;

        // P2: read bv2-3; stage A1(ky)->buf1
        #pragma unroll
        for (int nn = 2; nn < 4; ++nn) {
            bv[nn][0] = *(const f16x8*)(lds + bB + nn * 2048);
            bv[nn][1] = *(const f16x8*)(lds + bB + nn * 2048 + 64);
        }
        STAGE(0, 1, 1, ky);
        BARX; MFMAQ(0, 1); BARX;

        // P3: read av4-7; stage B0(kx+2)->buf0
        #pragma unroll
        for (int mm = 4; mm < 8; ++mm) {
            av[mm][0] = *(const f16x8*)(lds + aB + mm * 2048);
            av[mm][1] = *(const f16x8*)(lds + aB + mm * 2048 + 64);
        }
        if (!last) STAGE(1, 0, 0, kx + 2);
        BARX; MFMAQ(1, 0); BARX;

        // P4: stage B1(kx+2)->buf0; counted wait -> tile ky ready
        if (!last) STAGE(1, 0, 1, kx + 2);
        BARX; MFMAQ(1, 1);
        if (!last) { VMC4; } else { VMC0; }
        BARX;

        // ======== tile ky from buf1 ========
        // P5: read av0-3 + bv0-1; stage A0(kx+2)->buf0
        #pragma unroll
        for (int mm = 0; mm < 4; ++mm) {
            av[mm][0] = *(const f16x8*)(lds + aB + 32768 + mm * 2048);
            av[mm][1] = *(const f16x8*)(lds + aB + 32768 + mm * 2048 + 64);
        }
        #pragma unroll
        for (int nn = 0; nn < 2; ++nn) {
            bv[nn][0] = *(const f16x8*)(lds + bB + 32768 + nn * 2048);
            bv[nn][1] = *(const f16x8*)(lds + bB + 32768 + nn * 2048 + 64);
        }
        if (!last) STAGE(0, 0, 0, kx + 2);
        BARX; MFMAQ(0, 0); BARX;

        // P6: read bv2-3; stage A1(kx+2)->buf0
        #pragma unroll
        for (int nn = 2; nn < 4; ++nn) {
            bv[nn][0] = *(const f16x8*)(lds + bB + 32768 + nn * 2048);
            bv[nn][1] = *(const f16x8*)(lds + bB + 32768 + nn * 2048 + 64);
        }
        if (!last) STAGE(0, 0, 1, kx + 2);
        BARX; MFMAQ(0, 1); BARX;

        // P7: read av4-7; stage B0(ky+2)->buf1
        #pragma unroll
        for (int mm = 4; mm < 8; ++mm) {
            av[mm][0] = *(const f16x8*)(lds + aB + 32768 + mm * 2048);
            av[mm][1] = *(const f16x8*)(lds + aB + 32768 + mm * 2048 + 64);
        }
        if (!last) STAGE(1, 1, 0, ky + 2);
        BARX; MFMAQ(1, 0); BARX;

        // P8: stage B1(ky+2)->buf1; counted wait -> tile kx+2 ready
        if (!last) STAGE(1, 1, 1, ky + 2);
        BARX; MFMAQ(1, 1);
        if (!last) VMC4;
        BARX;
    }

    // ---- epilogue: C/D layout col=lane&15, row=(lane>>4)*4+r ----
    float lsum = 0.f;
    #pragma unroll
    for (int m = 0; m < 8; ++m) {
        #pragma unroll
        for (int r = 0; r < 4; ++r) {
            int orow = row0 + wr * 128 + m * 16 + l4 * 4 + r;
            float rowacc = 0.f;
            #pragma unroll
            for (int n = 0; n < 4; ++n) {
                int ocol = col0 + wc * 64 + n * 16 + l15;
                float val = acc[m][n][r];
                if constexpr (MODE == 0) {
                    _Float16 hb = (_Float16)(1.0f - val);
                    Cout[(size_t)orow * NM + ocol] = hb;
                    float fb = (float)hb;
                    rowacc += fb * fb;
                } else if constexpr (MODE == 1) {
                    Cout[(size_t)orow * NM + ocol] = (_Float16)(val * sv[ocol]);
                } else if constexpr (MODE == 2) {
                    float tens = ra[ocol] + rb[orow] - 2.0f * val;
                    Cout[(size_t)orow * NM + ocol] = (_Float16)expf(-2.0f * tens);
                } else {
                    float tens = ra[ocol] + rb[orow] - 2.0f * val;
                    float tv = su[ocol] * (float)Smat[(size_t)orow * NM + ocol] * sv[orow];
                    lsum += tens * tv;
                }
            }
            if constexpr (MODE == 0) {
                rowacc += __shfl_xor(rowacc, 1);
                rowacc += __shfl_xor(rowacc, 2);
                rowacc += __shfl_xor(rowacc, 4);
                rowacc += __shfl_xor(rowacc, 8);
                if (l15 == 0) atomicAdd(&rsum_out[orow], rowacc * PCONST);
            }
        }
    }
    if constexpr (MODE == 3) {
        for (int o = 32; o > 0; o >>= 1) lsum += __shfl_xor(lsum, o);
        float* redm = (float*)lds;
        __syncthreads();
        if (lane == 0) redm[w] = lsum;
        __syncthreads();
        if (tid == 0) {
            float t = 0.f;
            #pragma unroll
            for (int k = 0; k < 8; ++k) t += redm[k];
            atomicAdd(gm, t);
        }
    }
}

// ---------------- transpose: STr[i][j] = S[j][i] (fp16, 64x64 tiles) ----------------
__global__ void __launch_bounds__(256)
transpose16(const _Float16* __restrict__ S, _Float16* __restrict__ STr) {
    __shared__ _Float16 tile[64][65];
    int b = blockIdx.x;                  // 4096 = 64 x 64 tiles
    int jb = b >> 6, ib = b & 63;
    int j0 = jb * 64, i0 = ib * 64;
    int tid = threadIdx.x;
    int r = tid >> 2, c0 = (tid & 3) * 16;
    f16x8 v0 = *(const f16x8*)(S + (size_t)(j0 + r) * NM + i0 + c0);
    f16x8 v1 = *(const f16x8*)(S + (size_t)(j0 + r) * NM + i0 + c0 + 8);
    #pragma unroll
    for (int e = 0; e < 8; ++e) { tile[r][c0 + e] = v0[e]; tile[r][c0 + 8 + e] = v1[e]; }
    __syncthreads();
    f16x8 o0, o1;
    #pragma unroll
    for (int e = 0; e < 8; ++e) { o0[e] = tile[c0 + e][r]; o1[e] = tile[c0 + 8 + e][r]; }
    *(f16x8*)(STr + (size_t)(i0 + r) * NM + j0 + c0) = o0;
    *(f16x8*)(STr + (size_t)(i0 + r) * NM + j0 + c0 + 8) = o1;
}

// ---------------- sinkhorn matvec: rout[j] = PCONST / dot(M[j,:], rin) ----------------
template<int FIRST>
__global__ void __launch_bounds__(256)
matvec_row(const _Float16* __restrict__ M, const float* __restrict__ rin,
           float* __restrict__ rout) {
    int j = blockIdx.x;                  // 4096 rows
    int tid = threadIdx.x;
    const _Float16* row = M + (size_t)j * NM + tid * 16;
    float s = 0.f;
    f16x8 a0 = *(const f16x8*)(row);
    f16x8 a1 = *(const f16x8*)(row + 8);
    if constexpr (FIRST) {
        #pragma unroll
        for (int e = 0; e < 8; ++e) s += (float)a0[e] + (float)a1[e];
    } else {
        const float* rp = rin + tid * 16;
        f32x4 r0 = *(const f32x4*)(rp);
        f32x4 r1 = *(const f32x4*)(rp + 4);
        f32x4 r2 = *(const f32x4*)(rp + 8);
        f32x4 r3 = *(const f32x4*)(rp + 12);
        #pragma unroll
        for (int e = 0; e < 4; ++e) {
            s += (float)a0[e] * r0[e];
            s += (float)a0[e + 4] * r1[e];
            s += (float)a1[e] * r2[e];
            s += (float)a1[e + 4] * r3[e];
        }
    }
    for (int o = 32; o > 0; o >>= 1) s += __shfl_xor(s, o);
    __shared__ float red[4];
    if ((tid & 63) == 0) red[tid >> 6] = s;
    __syncthreads();
    if (tid == 0) rout[j] = PCONST / (red[0] + red[1] + red[2] + red[3]);
}

// ---------------- write T = u (.) K (.) v, row-major via LDS transpose ----------------
__global__ void write_T(const _Float16* __restrict__ S, const float* __restrict__ u,
                        const float* __restrict__ v, float* __restrict__ T) {
    __shared__ float tile[64][65];
    int b = blockIdx.x;                  // 4096 = 64 x 64 tiles
    int jb = b >> 6, ibk = b & 63;
    int j0 = jb * 64, i0 = ibk * 64;
    int tid = threadIdx.x;
    #pragma unroll
    for (int it = 0; it < 16; ++it) {
        int lin = it * 256 + tid;
        int jr = lin >> 6, ic = lin & 63;
        tile[jr][ic] = u[i0 + ic] * (float)S[(size_t)(j0 + jr) * NM + i0 + ic] * v[j0 + jr];
    }
    __syncthreads();
    #pragma unroll
    for (int it = 0; it < 16; ++it) {
        int lin = it * 256 + tid;
        int ir = lin >> 6, jc = lin & 63;
        T[(size_t)(i0 + ir) * NM + j0 + jc] = tile[jc][ir];
    }
}

// ---------------- host launcher ----------------
extern "C" void kernel_launch(void* const* d_in, const int* in_sizes, int n_in,
                              void* d_out, int out_size, void* d_ws, size_t ws_size,
                              hipStream_t stream) {
    const float* ft = (const float*)d_in[0];
    const float* fs = (const float*)d_in[1];
    float* out = (float*)d_out;
    char* ws = (char*)d_ws;

    _Float16* Ca = (_Float16*)(ws);                  // 32MB
    _Float16* Cb = (_Float16*)(ws + 33554432);       // 32MB
    _Float16* S  = (_Float16*)(ws + 67108864);       // 32MB (= K^T)
    _Float16* Pp = (_Float16*)(ws + 100663296);      // 32MB
    _Float16* zt = (_Float16*)(ws + 134217728);      // 2MB
    _Float16* zs = (_Float16*)(ws + 136314880);      // 2MB
    float* ra = (float*)(ws + 138412032);
    float* rb = ra + 4096;
    float* u  = ra + 8192;
    float* v  = ra + 12288;
    // Ap (iter-local MODE-1 A operand) and STr (sinkhorn-local K row-major) share
    // the regenerated-every-call scratch inside d_out's T region; lifetimes disjoint.
    _Float16* Ap  = (_Float16*)(out + 4);            // 32MB, 16B aligned
    _Float16* STr = Ap;

    init_misc<<<16, 256, 0, stream>>>(ra, rb, u, v, out);
    prep_z<<<8192, 256, 0, stream>>>(ft, fs, zt, zs);
    gemm8p<0><<<256, 512, GLDS, stream>>>(zt, zt, DD, Ca, nullptr, nullptr, ra,
                                          nullptr, nullptr, nullptr, nullptr);
    gemm8p<0><<<256, 512, GLDS, stream>>>(zs, zs, DD, Cb, nullptr, nullptr, rb,
                                          nullptr, nullptr, nullptr, nullptr);
    init_S<<<8192, 256, 0, stream>>>(S);

    for (int t = 0; t < 10; ++t) {
        scale_A<<<2048, 256, 0, stream>>>(Ca, u, Ap);
        gemm8p<1><<<256, 512, GLDS, stream>>>(Ap, S, NM, Pp, nullptr, nullptr, nullptr,
                                              nullptr, v, nullptr, nullptr);
        gemm8p<2><<<256, 512, GLDS, stream>>>(Cb, Pp, NM, S, ra, rb, nullptr,
                                              nullptr, nullptr, nullptr, nullptr);
        transpose16<<<4096, 256, 0, stream>>>(S, STr);
        matvec_row<1><<<4096, 256, 0, stream>>>(S, nullptr, v);
        for (int p = 0; p < NPAIR; ++p) {
            matvec_row<0><<<4096, 256, 0, stream>>>(STr, v, u);
            matvec_row<0><<<4096, 256, 0, stream>>>(S, u, v);
        }
    }

    // final tens evaluation with T_10, fused gm_loss, then materialize T
    scale_A<<<2048, 256, 0, stream>>>(Ca, u, Ap);
    gemm8p<1><<<256, 512, GLDS, stream>>>(Ap, S, NM, Pp, nullptr, nullptr, nullptr,
                                          nullptr, v, nullptr, nullptr);
    gemm8p<3><<<256, 512, GLDS, stream>>>(Cb, Pp, NM, nullptr, ra, rb, nullptr,
                                          u, v, S, out);
    write_T<<<4096, 256, 0, stream>>>(S, u, v, out + 1);
}

// Round 8
// 3139.521 us; speedup vs baseline: 1.8961x; 1.0941x over previous
//
#include <hip/hip_runtime.h>
#include <hip/hip_bf16.h>

#define NM 4096
#define DD 256
constexpr float PCONST = 1.0f / 4096.0f;   // p = q = 1/n
#define NPAIR 3                            // sinkhorn pairs (converged; contraction ~1.6e-3/pair)
#define GLDS 131072                        // 64KB A + 64KB B (double-buffered)

typedef __attribute__((ext_vector_type(8))) _Float16 f16x8;
typedef __attribute__((ext_vector_type(4))) float f32x4;

// ---------------- prep: z = (x - mean) / ||x - mean||, fp16 ----------------
__global__ void prep_z(const float* __restrict__ ft, const float* __restrict__ fs,
                       _Float16* __restrict__ zt, _Float16* __restrict__ zs) {
    int row = blockIdx.x;                 // 0..8191
    int tid = threadIdx.x;                // 256 == DD
    const float* src = (row < NM) ? (ft + (size_t)row * DD) : (fs + (size_t)(row - NM) * DD);
    _Float16* dst = (row < NM) ? (zt + (size_t)row * DD) : (zs + (size_t)(row - NM) * DD);
    float x = src[tid];
    __shared__ float red[4];
    float s = x;
    for (int o = 32; o > 0; o >>= 1) s += __shfl_xor(s, o);
    if ((tid & 63) == 0) red[tid >> 6] = s;
    __syncthreads();
    float mean = (red[0] + red[1] + red[2] + red[3]) * (1.0f / DD);
    float mc = x - mean;
    __syncthreads();
    float q = mc * mc;
    for (int o = 32; o > 0; o >>= 1) q += __shfl_xor(q, o);
    if ((tid & 63) == 0) red[tid >> 6] = q;
    __syncthreads();
    float ss = red[0] + red[1] + red[2] + red[3];
    float scale = 1.0f / sqrtf(ss);
    dst[tid] = (_Float16)(mc * scale);
}

// ---------------- init kernels ----------------
__global__ void init_misc(float* ra, float* rb, float* u, float* v, float* gmout) {
    int i = blockIdx.x * 256 + threadIdx.x;     // grid 16 -> 4096
    ra[i] = 0.f; rb[i] = 0.f; u[i] = PCONST; v[i] = PCONST;
    if (i == 0) gmout[0] = 0.f;
}
__global__ void init_S(_Float16* __restrict__ S) {
    size_t idx = ((size_t)blockIdx.x * 256 + threadIdx.x) * 8;  // grid 8192
    f16x8 one;
    #pragma unroll
    for (int e = 0; e < 8; ++e) one[e] = (_Float16)1.0f;
    *(f16x8*)(S + idx) = one;
}

// ---------------- A' = Ca (.) u (column scale), fp32 u (decorrelated rounding) ----------------
__global__ void scale_A(const _Float16* __restrict__ Ca, const float* __restrict__ u,
                        _Float16* __restrict__ Ap) {
    size_t base = ((size_t)blockIdx.x * 256 + threadIdx.x) * 8;
    size_t stride = (size_t)gridDim.x * 256 * 8;
    size_t total = (size_t)NM * NM;
    for (size_t idx = base; idx < total; idx += stride) {
        f16x8 c8 = *(const f16x8*)(Ca + idx);
        int k = (int)(idx & (NM - 1));
        f16x8 o8;
        #pragma unroll
        for (int e = 0; e < 8; ++e) o8[e] = (_Float16)((float)c8[e] * u[k + e]);
        *(f16x8*)(Ap + idx) = o8;
    }
}

// =====================================================================
// 8-phase 256x256 BT-GEMM, BK=64, 8 waves, 128KB dbuf LDS.
// LDS swizzle: 3-bit involution  byte ^= ((row&7)<<4)  (conflict-free
// ds_read_b128: bank-group = l4 ^ (l15&7), 2 lanes/group). Applied
// linear-dest + inverse-swizzled global src (rule #21). Counted vmcnt(4)
// at phases 4/8, setprio around MFMA clusters, 8x4-rect XCD block remap.
// out[row][col] = sum_k A[row][k]*B[col][k]  (A,B f16 row-major stride K)
// MODE 0: Cout=f16(1-acc), atomic row-mean-of-squares into rsum_out
// MODE 1: Cout=f16(acc*sv[col])
// MODE 2: tens=ra[col]+rb[row]-2*acc; Cout=f16(exp(-2*tens))
// MODE 3: tens as 2; T=su[col]*Smat[row][col]*sv[row]; atomicAdd(gm,sum)
// =====================================================================
#define BARX do { __builtin_amdgcn_s_barrier(); __builtin_amdgcn_sched_barrier(0); } while(0)
#define VMC4 asm volatile("s_waitcnt vmcnt(4)" ::: "memory")
#define VMC0 asm volatile("s_waitcnt vmcnt(0)" ::: "memory")

#define STAGE(matb, d, h, kt) do { \
    const char* _s = ((matb) ? Bb : Ab) + (size_t)((h) * 128) * lda + (size_t)(kt) * 128; \
    char* _dst = lds + ((matb) ? 65536 : 0) + (d) * 32768 + (h) * 16384; \
    __builtin_amdgcn_global_load_lds((const __attribute__((address_space(1))) unsigned int*)(_s + (size_t)sr0 * lda + sc0), \
        (__attribute__((address_space(3))) unsigned int*)(_dst + P0), 16, 0, 0); \
    __builtin_amdgcn_global_load_lds((const __attribute__((address_space(1))) unsigned int*)(_s + (size_t)sr1 * lda + sc1), \
        (__attribute__((address_space(3))) unsigned int*)(_dst + P1b), 16, 0, 0); \
  } while(0)

#define MFMAQ(MH, NH) do { \
    __builtin_amdgcn_s_setprio(1); \
    _Pragma("unroll") for (int mm = 0; mm < 4; ++mm) \
    _Pragma("unroll") for (int nn = 0; nn < 2; ++nn) \
    _Pragma("unroll") for (int ks = 0; ks < 2; ++ks) \
        acc[(MH)*4+mm][(NH)*2+nn] = __builtin_amdgcn_mfma_f32_16x16x32_f16( \
            av[(MH)*4+mm][ks], bv[(NH)*2+nn][ks], acc[(MH)*4+mm][(NH)*2+nn], 0, 0, 0); \
    __builtin_amdgcn_s_setprio(0); \
  } while(0)

template<int MODE>
__global__ void __launch_bounds__(512, 2)
gemm8p(const _Float16* __restrict__ A, const _Float16* __restrict__ B, const int K,
       _Float16* __restrict__ Cout,
       const float* __restrict__ ra, const float* __restrict__ rb,
       float* __restrict__ rsum_out,
       const float* __restrict__ su, const float* __restrict__ sv,
       const _Float16* __restrict__ Smat, float* __restrict__ gm)
{
    extern __shared__ __align__(16) char lds[];
    const int tid = threadIdx.x;
    const int lane = tid & 63, w = tid >> 6;
    const int wr = w >> 2, wc = w & 3;
    // XCD-aware bijective remap: XCD x (= blockIdx&7) gets an 8(bi) x 4(bj) rect
    const int xcd = blockIdx.x & 7, bidx = blockIdx.x >> 3;
    const int bi = ((xcd & 1) << 3) + (bidx & 7);
    const int bj = ((xcd >> 1) << 2) + (bidx >> 3);
    const int row0 = bi * 256, col0 = bj * 256;
    const int l15 = lane & 15, l4 = lane >> 4;

    // staging constants: physical chunk P -> logical L (involution, key=(row&7)<<4)
    const int P0 = tid * 16, P1b = P0 + 8192;
    const int Ls0 = P0 ^ (((P0 >> 7) & 7) << 4);
    const int Ls1 = P1b ^ (((P1b >> 7) & 7) << 4);
    const int sr0 = Ls0 >> 7, sc0 = Ls0 & 127;
    const int sr1 = Ls1 >> 7, sc1 = Ls1 & 127;

    const size_t lda = (size_t)K * 2;
    const char* Ab = (const char*)A + (size_t)row0 * lda;
    const char* Bb = (const char*)B + (size_t)col0 * lda;

    // ds_read bases (+ d*32768 + frag*2048); ks=1 column is base ^ 64
    const int key = (l15 & 7) << 4;
    const int aB  = wr * 16384 + l15 * 128 + ((l4 * 16) ^ key);
    const int aBx = aB ^ 64;
    const int bB  = 65536 + (wc >> 1) * 16384 + ((wc & 1) * 64 + l15) * 128 + ((l4 * 16) ^ key);
    const int bBx = bB ^ 64;

    f32x4 acc[8][4] = {};
    f16x8 av[8][2], bv[4][2];

    // ---- prologue: B(0),A(0),B(1) halves ----
    STAGE(1, 0, 0, 0); STAGE(1, 0, 1, 0);
    STAGE(0, 0, 0, 0); STAGE(0, 0, 1, 0);
    STAGE(1, 1, 0, 1); STAGE(1, 1, 1, 1);
    VMC4;                       // tile0 A+B landed; B(1) in flight
    BARX;

    const int niter = K >> 7;   // K / 128, two K-tiles per iteration
    for (int i = 0; i < niter; ++i) {
        const int kx = 2 * i, ky = kx + 1;
        const bool last = (i == niter - 1);

        // ======== tile kx from buf0 ========
        // P1: read av0-3 + bv0-1; stage A0(ky)->buf1
        #pragma unroll
        for (int mm = 0; mm < 4; ++mm) {
            av[mm][0] = *(const f16x8*)(lds + aB + mm * 2048);
            av[mm][1] = *(const f16x8*)(lds + aBx + mm * 2048);
        }
        #pragma unroll
        for (int nn = 0; nn < 2; ++nn) {
            bv[nn][0] = *(const f16x8*)(lds + bB + nn * 2048);
            bv[nn][1] = *(const f16x8*)(lds + bBx + nn * 2048);
        }
        STAGE(0, 1, 0, ky);
        BARX; MFMAQ(0, 0); BARX;

        // P2: read bv2-3; stage A1(ky)->buf1
        #pragma unroll
        for (int nn = 2; nn < 4; ++nn) {
            bv[nn][0] = *(const f16x8*)(lds + bB + nn * 2048);
            bv[nn][1] = *(const f16x8*)(lds + bBx + nn * 2048);
        }
        STAGE(0, 1, 1, ky);
        BARX; MFMAQ(0, 1); BARX;

        // P3: read av4-7; stage B0(kx+2)->buf0
        #pragma unroll
        for (int mm = 4; mm < 8; ++mm) {
            av[mm][0] = *(const f16x8*)(lds + aB + mm * 2048);
            av[mm][1] = *(const f16x8*)(lds + aBx + mm * 2048);
        }
        if (!last) STAGE(1, 0, 0, kx + 2);
        BARX; MFMAQ(1, 0); BARX;

        // P4: stage B1(kx+2)->buf0; counted wait -> tile ky ready
        if (!last) STAGE(1, 0, 1, kx + 2);
        BARX; MFMAQ(1, 1);
        if (!last) { VMC4; } else { VMC0; }
        BARX;

        // ======== tile ky from buf1 ========
        // P5: read av0-3 + bv0-1; stage A0(kx+2)->buf0
        #pragma unroll
        for (int mm = 0; mm < 4; ++mm) {
            av[mm][0] = *(const f16x8*)(lds + aB + 32768 + mm * 2048);
            av[mm][1] = *(const f16x8*)(lds + aBx + 32768 + mm * 2048);
        }
        #pragma unroll
        for (int nn = 0; nn < 2; ++nn) {
            bv[nn][0] = *(const f16x8*)(lds + bB + 32768 + nn * 2048);
            bv[nn][1] = *(const f16x8*)(lds + bBx + 32768 + nn * 2048);
        }
        if (!last) STAGE(0, 0, 0, kx + 2);
        BARX; MFMAQ(0, 0); BARX;

        // P6: read bv2-3; stage A1(kx+2)->buf0
        #pragma unroll
        for (int nn = 2; nn < 4; ++nn) {
            bv[nn][0] = *(const f16x8*)(lds + bB + 32768 + nn * 2048);
            bv[nn][1] = *(const f16x8*)(lds + bBx + 32768 + nn * 2048);
        }
        if (!last) STAGE(0, 0, 1, kx + 2);
        BARX; MFMAQ(0, 1); BARX;

        // P7: read av4-7; stage B0(ky+2)->buf1
        #pragma unroll
        for (int mm = 4; mm < 8; ++mm) {
            av[mm][0] = *(const f16x8*)(lds + aB + 32768 + mm * 2048);
            av[mm][1] = *(const f16x8*)(lds + aBx + 32768 + mm * 2048);
        }
        if (!last) STAGE(1, 1, 0, ky + 2);
        BARX; MFMAQ(1, 0); BARX;

        // P8: stage B1(ky+2)->buf1; counted wait -> tile kx+2 ready
        if (!last) STAGE(1, 1, 1, ky + 2);
        BARX; MFMAQ(1, 1);
        if (!last) VMC4;
        BARX;
    }

    // ---- epilogue: C/D layout col=lane&15, row=(lane>>4)*4+r ----
    float lsum = 0.f;
    #pragma unroll
    for (int m = 0; m < 8; ++m) {
        #pragma unroll
        for (int r = 0; r < 4; ++r) {
            int orow = row0 + wr * 128 + m * 16 + l4 * 4 + r;
            float rowacc = 0.f;
            #pragma unroll
            for (int n = 0; n < 4; ++n) {
                int ocol = col0 + wc * 64 + n * 16 + l15;
                float val = acc[m][n][r];
                if constexpr (MODE == 0) {
                    _Float16 hb = (_Float16)(1.0f - val);
                    Cout[(size_t)orow * NM + ocol] = hb;
                    float fb = (float)hb;
                    rowacc += fb * fb;
                } else if constexpr (MODE == 1) {
                    Cout[(size_t)orow * NM + ocol] = (_Float16)(val * sv[ocol]);
                } else if constexpr (MODE == 2) {
                    float tens = ra[ocol] + rb[orow] - 2.0f * val;
                    Cout[(size_t)orow * NM + ocol] = (_Float16)expf(-2.0f * tens);
                } else {
                    float tens = ra[ocol] + rb[orow] - 2.0f * val;
                    float tv = su[ocol] * (float)Smat[(size_t)orow * NM + ocol] * sv[orow];
                    lsum += tens * tv;
                }
            }
            if constexpr (MODE == 0) {
                rowacc += __shfl_xor(rowacc, 1);
                rowacc += __shfl_xor(rowacc, 2);
                rowacc += __shfl_xor(rowacc, 4);
                rowacc += __shfl_xor(rowacc, 8);
                if (l15 == 0) atomicAdd(&rsum_out[orow], rowacc * PCONST);
            }
        }
    }
    if constexpr (MODE == 3) {
        for (int o = 32; o > 0; o >>= 1) lsum += __shfl_xor(lsum, o);
        float* redm = (float*)lds;
        __syncthreads();
        if (lane == 0) redm[w] = lsum;
        __syncthreads();
        if (tid == 0) {
            float t = 0.f;
            #pragma unroll
            for (int k = 0; k < 8; ++k) t += redm[k];
            atomicAdd(gm, t);
        }
    }
}

// ---------------- transpose: STr[i][j] = S[j][i] (fp16, 64x64 tiles) ----------------
__global__ void __launch_bounds__(256)
transpose16(const _Float16* __restrict__ S, _Float16* __restrict__ STr) {
    __shared__ _Float16 tile[64][65];
    int b = blockIdx.x;                  // 4096 = 64 x 64 tiles
    int jb = b >> 6, ib = b & 63;
    int j0 = jb * 64, i0 = ib * 64;
    int tid = threadIdx.x;
    int r = tid >> 2, c0 = (tid & 3) * 16;
    f16x8 v0 = *(const f16x8*)(S + (size_t)(j0 + r) * NM + i0 + c0);
    f16x8 v1 = *(const f16x8*)(S + (size_t)(j0 + r) * NM + i0 + c0 + 8);
    #pragma unroll
    for (int e = 0; e < 8; ++e) { tile[r][c0 + e] = v0[e]; tile[r][c0 + 8 + e] = v1[e]; }
    __syncthreads();
    f16x8 o0, o1;
    #pragma unroll
    for (int e = 0; e < 8; ++e) { o0[e] = tile[c0 + e][r]; o1[e] = tile[c0 + 8 + e][r]; }
    *(f16x8*)(STr + (size_t)(i0 + r) * NM + j0 + c0) = o0;
    *(f16x8*)(STr + (size_t)(i0 + r) * NM + j0 + c0 + 8) = o1;
}

// ---------------- sinkhorn matvec: rout[j] = PCONST / dot(M[j,:], rin) ----------------
template<int FIRST>
__global__ void __launch_bounds__(256)
matvec_row(const _Float16* __restrict__ M, const float* __restrict__ rin,
           float* __restrict__ rout) {
    int j = blockIdx.x;                  // 4096 rows
    int tid = threadIdx.x;
    const _Float16* row = M + (size_t)j * NM + tid * 16;
    float s = 0.f;
    f16x8 a0 = *(const f16x8*)(row);
    f16x8 a1 = *(const f16x8*)(row + 8);
    if constexpr (FIRST) {
        #pragma unroll
        for (int e = 0; e < 8; ++e) s += (float)a0[e] + (float)a1[e];
    } else {
        const float* rp = rin + tid * 16;
        f32x4 r0 = *(const f32x4*)(rp);
        f32x4 r1 = *(const f32x4*)(rp + 4);
        f32x4 r2 = *(const f32x4*)(rp + 8);
        f32x4 r3 = *(const f32x4*)(rp + 12);
        #pragma unroll
        for (int e = 0; e < 4; ++e) {
            s += (float)a0[e] * r0[e];
            s += (float)a0[e + 4] * r1[e];
            s += (float)a1[e] * r2[e];
            s += (float)a1[e + 4] * r3[e];
        }
    }
    for (int o = 32; o > 0; o >>= 1) s += __shfl_xor(s, o);
    __shared__ float red[4];
    if ((tid & 63) == 0) red[tid >> 6] = s;
    __syncthreads();
    if (tid == 0) rout[j] = PCONST / (red[0] + red[1] + red[2] + red[3]);
}

// ---------------- write T = u (.) K (.) v, row-major via LDS transpose ----------------
__global__ void write_T(const _Float16* __restrict__ S, const float* __restrict__ u,
                        const float* __restrict__ v, float* __restrict__ T) {
    __shared__ float tile[64][65];
    int b = blockIdx.x;                  // 4096 = 64 x 64 tiles
    int jb = b >> 6, ibk = b & 63;
    int j0 = jb * 64, i0 = ibk * 64;
    int tid = threadIdx.x;
    #pragma unroll
    for (int it = 0; it < 16; ++it) {
        int lin = it * 256 + tid;
        int jr = lin >> 6, ic = lin & 63;
        tile[jr][ic] = u[i0 + ic] * (float)S[(size_t)(j0 + jr) * NM + i0 + ic] * v[j0 + jr];
    }
    __syncthreads();
    #pragma unroll
    for (int it = 0; it < 16; ++it) {
        int lin = it * 256 + tid;
        int ir = lin >> 6, jc = lin & 63;
        T[(size_t)(i0 + ir) * NM + j0 + jc] = tile[jc][ir];
    }
}

// ---------------- host launcher ----------------
extern "C" void kernel_launch(void* const* d_in, const int* in_sizes, int n_in,
                              void* d_out, int out_size, void* d_ws, size_t ws_size,
                              hipStream_t stream) {
    const float* ft = (const float*)d_in[0];
    const float* fs = (const float*)d_in[1];
    float* out = (float*)d_out;
    char* ws = (char*)d_ws;

    _Float16* Ca = (_Float16*)(ws);                  // 32MB
    _Float16* Cb = (_Float16*)(ws + 33554432);       // 32MB
    _Float16* S  = (_Float16*)(ws + 67108864);       // 32MB (= K^T)
    _Float16* Pp = (_Float16*)(ws + 100663296);      // 32MB
    _Float16* zt = (_Float16*)(ws + 134217728);      // 2MB
    _Float16* zs = (_Float16*)(ws + 136314880);      // 2MB
    float* ra = (float*)(ws + 138412032);
    float* rb = ra + 4096;
    float* u  = ra + 8192;
    float* v  = ra + 12288;
    // Ap (iter-local MODE-1 A operand) and STr (sinkhorn-local K row-major) share
    // the regenerated-every-call scratch inside d_out's T region; lifetimes disjoint.
    _Float16* Ap  = (_Float16*)(out + 4);            // 32MB, 16B aligned
    _Float16* STr = Ap;

    init_misc<<<16, 256, 0, stream>>>(ra, rb, u, v, out);
    prep_z<<<8192, 256, 0, stream>>>(ft, fs, zt, zs);
    gemm8p<0><<<256, 512, GLDS, stream>>>(zt, zt, DD, Ca, nullptr, nullptr, ra,
                                          nullptr, nullptr, nullptr, nullptr);
    gemm8p<0><<<256, 512, GLDS, stream>>>(zs, zs, DD, Cb, nullptr, nullptr, rb,
                                          nullptr, nullptr, nullptr, nullptr);
    init_S<<<8192, 256, 0, stream>>>(S);

    for (int t = 0; t < 10; ++t) {
        scale_A<<<2048, 256, 0, stream>>>(Ca, u, Ap);
        gemm8p<1><<<256, 512, GLDS, stream>>>(Ap, S, NM, Pp, nullptr, nullptr, nullptr,
                                              nullptr, v, nullptr, nullptr);
        gemm8p<2><<<256, 512, GLDS, stream>>>(Cb, Pp, NM, S, ra, rb, nullptr,
                                              nullptr, nullptr, nullptr, nullptr);
        transpose16<<<4096, 256, 0, stream>>>(S, STr);
        matvec_row<1><<<4096, 256, 0, stream>>>(S, nullptr, v);
        for (int p = 0; p < NPAIR; ++p) {
            matvec_row<0><<<4096, 256, 0, stream>>>(STr, v, u);
            matvec_row<0><<<4096, 256, 0, stream>>>(S, u, v);
        }
    }

    // final tens evaluation with T_10, fused gm_loss, then materialize T
    scale_A<<<2048, 256, 0, stream>>>(Ca, u, Ap);
    gemm8p<1><<<256, 512, GLDS, stream>>>(Ap, S, NM, Pp, nullptr, nullptr, nullptr,
                                          nullptr, v, nullptr, nullptr);
    gemm8p<3><<<256, 512, GLDS, stream>>>(Cb, Pp, NM, nullptr, ra, rb, nullptr,
                                          u, v, S, out);
    write_T<<<4096, 256, 0, stream>>>(S, u, v, out + 1);
}